// Round 1
// baseline (635.219 us; speedup 1.0000x reference)
//
#include <hip/hip_runtime.h>
#include <math.h>

// Fused SpectralPooling: out = (A (x) A (x) A) * x per (b,c) volume,
// A[j][n] = sum_{k<28} D32[k][j] * D64[k][n]  (32x64), computed on device.

__global__ void init_A(float* __restrict__ ws) {
    int g = blockIdx.x * blockDim.x + threadIdx.x;  // 0..2047
    if (g >= 2048) return;
    int j = g >> 6;   // 0..31
    int n = g & 63;   // 0..63
    const double PI = 3.14159265358979323846;
    double acc = 0.0;
    for (int k = 0; k < 28; ++k) {
        double s32 = (k == 0) ? sqrt(1.0 / 32.0) : sqrt(2.0 / 32.0);
        double s64 = (k == 0) ? sqrt(1.0 / 64.0) : sqrt(2.0 / 64.0);
        acc += s32 * cos(PI * (2.0 * j + 1.0) * (double)k / 64.0)
             * s64 * cos(PI * (2.0 * n + 1.0) * (double)k / 128.0);
    }
    ws[g] = (float)acc;                 // A  row-major [32][64]
    ws[2048 + n * 32 + j] = (float)acc; // At row-major [64][32]
}

// grid = 256 blocks (one per (b,c) volume), 512 threads (8 waves).
__global__ __launch_bounds__(512, 2) void spectral_kernel(
    const float* __restrict__ x, const float* __restrict__ ws,
    float* __restrict__ out)
{
    const float* __restrict__ A  = ws;          // [32][64]
    const float* __restrict__ At = ws + 2048;   // [64][32]

    // padded rows: 68 floats = 272 B (16B-aligned rows, bank stride 4)
    __shared__ __align__(16) float S [2][64][68];  // slab pair   (34.8 KB)
    __shared__ __align__(16) float vT[2][32][68];  // v transposed (17.4 KB)
    __shared__ __align__(16) float U [2][32][32];  // u            ( 8 KB)

    const int t    = threadIdx.x;
    const int b    = blockIdx.x;
    const int lane = t & 63;
    const int w    = __builtin_amdgcn_readfirstlane(t >> 6); // wave id 0..7 (SGPR)
    const int sl   = w & 1;            // phase-V slab
    const int kb   = (w >> 1) * 8;     // phase-V k-base (uniform)
    const int jb   = w * 4;            // phase-U j-base (uniform)
    const int k32  = t & 31;
    const int sl2  = (t >> 5) & 1;     // phase-U slab (per-lane)
    const int j0   = t >> 5;           // 0..15 (ACC/epilogue j)

    float acc0[32], acc1[32];
#pragma unroll
    for (int i = 0; i < 32; ++i) { acc0[i] = 0.f; acc1[i] = 0.f; }

    const float* xb = x + (size_t)b * 262144;

    // prefetch slab pair 0 into registers
    float4 r0, r1, r2, r3;
    {
        const float4* src = (const float4*)xb;
        r0 = src[t]; r1 = src[t + 512]; r2 = src[t + 1024]; r3 = src[t + 1536];
    }

    for (int it = 0; it < 32; ++it) {
        // ---- stage prefetched pair into LDS ----
        {
            int q;
            q = t;        *(float4*)&S[q >> 10][(q >> 4) & 63][(q & 15) * 4] = r0;
            q = t + 512;  *(float4*)&S[q >> 10][(q >> 4) & 63][(q & 15) * 4] = r1;
            q = t + 1024; *(float4*)&S[q >> 10][(q >> 4) & 63][(q & 15) * 4] = r2;
            q = t + 1536; *(float4*)&S[q >> 10][(q >> 4) & 63][(q & 15) * 4] = r3;
        }
        __syncthreads();  // b1

        // issue next prefetch (latency hidden behind phase V compute)
        if (it < 31) {
            const float4* src = (const float4*)(xb + (size_t)(it + 1) * 8192);
            r0 = src[t]; r1 = src[t + 512]; r2 = src[t + 1024]; r3 = src[t + 1536];
        }

        // ---- phase V: v[m][k] = sum_p A[k][p] * S[m][p] ----
        // lane = m; wave covers 8 k of one slab; A via scalar loads
        float vr[8];
#pragma unroll
        for (int kk = 0; kk < 8; ++kk) vr[kk] = 0.f;
#pragma unroll
        for (int p4 = 0; p4 < 16; ++p4) {
            float4 s = *(const float4*)&S[sl][lane][p4 * 4];
#pragma unroll
            for (int kk = 0; kk < 8; ++kk) {
                const float* Ak = A + (kb + kk) * 64 + p4 * 4;  // uniform -> s_load
                vr[kk] += Ak[0] * s.x + Ak[1] * s.y + Ak[2] * s.z + Ak[3] * s.w;
            }
        }
#pragma unroll
        for (int kk = 0; kk < 8; ++kk) vT[sl][kb + kk][lane] = vr[kk];
        __syncthreads();  // b2

        // ---- phase U: u[j][k] = sum_m A[j][m] * vT[k][m] ----
        // lane = (k, slab); wave covers 4 j; A via scalar loads
        float ur[4] = {0.f, 0.f, 0.f, 0.f};
#pragma unroll
        for (int m4 = 0; m4 < 16; ++m4) {
            float4 v = *(const float4*)&vT[sl2][k32][m4 * 4];
#pragma unroll
            for (int jj = 0; jj < 4; ++jj) {
                const float* Aj = A + (jb + jj) * 64 + m4 * 4;  // uniform -> s_load
                ur[jj] += Aj[0] * v.x + Aj[1] * v.y + Aj[2] * v.z + Aj[3] * v.w;
            }
        }
#pragma unroll
        for (int jj = 0; jj < 4; ++jj) U[sl2][jb + jj][k32] = ur[jj];
        __syncthreads();  // b3

        // ---- phase ACC: acc[i] += At[n][i] * u[j][k] for both slabs ----
        float u00 = U[0][j0][k32];
        float u01 = U[0][j0 + 16][k32];
        float u10 = U[1][j0][k32];
        float u11 = U[1][j0 + 16][k32];
        const float* a0 = At + (size_t)(2 * it) * 32;      // uniform -> s_load
        const float* a1 = At + (size_t)(2 * it + 1) * 32;
#pragma unroll
        for (int i = 0; i < 32; ++i) {
            acc0[i] += a0[i] * u00 + a1[i] * u10;
            acc1[i] += a0[i] * u01 + a1[i] * u11;
        }
    }

    // ---- epilogue: out[b][i][j][k] ----
    float* ob = out + (size_t)b * 32768;
#pragma unroll
    for (int i = 0; i < 32; ++i) {
        ob[i * 1024 + j0 * 32 + k32]        = acc0[i];
        ob[i * 1024 + (j0 + 16) * 32 + k32] = acc1[i];
    }
}

extern "C" void kernel_launch(void* const* d_in, const int* in_sizes, int n_in,
                              void* d_out, int out_size, void* d_ws, size_t ws_size,
                              hipStream_t stream) {
    const float* x = (const float*)d_in[0];
    float* out = (float*)d_out;
    float* ws  = (float*)d_ws;   // [0,2048): A ; [2048,4096): At

    init_A<<<2, 1024, 0, stream>>>(ws);
    spectral_kernel<<<256, 512, 0, stream>>>(x, ws, out);
}

// Round 2
// 391.599 us; speedup vs baseline: 1.6221x; 1.6221x over previous
//
#include <hip/hip_runtime.h>
#include <hip/hip_bf16.h>
#include <math.h>

// Fused SpectralPooling: out = (A (x) A (x) A) * x per (b,c) volume,
// A[j][n] = sum_{k<28} D32[k][j] * D64[k][n]  (32x64).
// Phases V,U (64->32 contractions) on MFMA bf16; final n-contraction fp32 VALU.

typedef short short8 __attribute__((ext_vector_type(8)));
typedef float f32x4 __attribute__((ext_vector_type(4)));

__global__ void init_A(float* __restrict__ ws) {
    int g = blockIdx.x * blockDim.x + threadIdx.x;  // 0..2047
    if (g >= 2048) return;
    int j = g >> 6;   // 0..31
    int n = g & 63;   // 0..63
    const double PI = 3.14159265358979323846;
    double acc = 0.0;
    for (int k = 0; k < 28; ++k) {
        double s32 = (k == 0) ? sqrt(1.0 / 32.0) : sqrt(2.0 / 32.0);
        double s64 = (k == 0) ? sqrt(1.0 / 64.0) : sqrt(2.0 / 64.0);
        acc += s32 * cos(PI * (2.0 * j + 1.0) * (double)k / 64.0)
             * s64 * cos(PI * (2.0 * n + 1.0) * (double)k / 128.0);
    }
    ws[g] = (float)acc;                 // A  row-major [32][64]
    ws[2048 + n * 32 + j] = (float)acc; // At row-major [64][32]
}

__device__ inline unsigned pk_bf16(float a, float b) {
    union { __hip_bfloat162 h2; unsigned u; } c;
    c.h2 = __float22bfloat162_rn(make_float2(a, b));
    return c.u;
}

// grid = 256 blocks (one per (b,c) volume), 512 threads (8 waves).
__global__ __launch_bounds__(512, 2) void spectral_kernel(
    const float* __restrict__ x, const float* __restrict__ ws,
    float* __restrict__ out)
{
    // LDS (pad rows so b128 frag reads stay 16B-aligned, <=2-way banks)
    __shared__ __align__(16) unsigned short Xbf[2][64][72]; // x slabs, bf16 (18.4 KB)
    __shared__ __align__(16) unsigned short Vbf[2][32][72]; // v[k][m], bf16 ( 9.2 KB)
    __shared__ __align__(16) float          Ubuf[2][32][36];// u[j][k], fp32 ( 9.2 KB)
    __shared__ __align__(16) unsigned short Abf[32][72];    // A bf16        ( 4.6 KB)
    __shared__ __align__(16) float          Atl[64][32];    // At fp32       ( 8.2 KB)

    const int t    = threadIdx.x;
    const int b    = blockIdx.x;
    const int lane = t & 63;
    const int l15  = lane & 15;
    const int q4   = lane >> 4;                              // quad 0..3
    const int w    = __builtin_amdgcn_readfirstlane(t >> 6); // wave 0..7
    const int sl   = w & 1;                                  // slab
    const int ws4  = w >> 1;                                 // 0..3
    const int m0   = ws4 * 16;                               // phase-V m-tile
    const int kt2  = ws4 & 1;                                // phase-U k-tile
    const int jt   = ws4 >> 1;                               // phase-U j-tile
    const int k32  = t & 31;
    const int j0   = t >> 5;                                 // 0..15

    // ---- stage A (bf16) and At (fp32) into LDS ----
    {
        const float* Ag  = ws;
        const float* Atg = ws + 2048;
        for (int q = t; q < 2048; q += 512) {
            float v = Ag[q];
            __hip_bfloat16 h = __float2bfloat16(v);
            Abf[q >> 6][q & 63] = *(unsigned short*)&h;
            ((float*)Atl)[q] = Atg[q];
        }
    }

    float acc0[32], acc1[32];
#pragma unroll
    for (int i = 0; i < 32; ++i) { acc0[i] = 0.f; acc1[i] = 0.f; }

    const float* xb = x + (size_t)b * 262144;

    // prefetch slab pair 0
    float4 r0, r1, r2, r3;
    {
        const float4* src = (const float4*)xb;
        r0 = src[t]; r1 = src[t + 512]; r2 = src[t + 1024]; r3 = src[t + 1536];
    }

    __syncthreads();  // A/At staged

    // constant B-fragments of A (shared by phases V and U), kept in VGPRs:
    // bv[r][c]: element j = A[r*16 + l15][c*32 + q4*8 + j]
    short8 bv00 = *(const short8*)&Abf[l15][q4 * 8];
    short8 bv01 = *(const short8*)&Abf[l15][32 + q4 * 8];
    short8 bv10 = *(const short8*)&Abf[16 + l15][q4 * 8];
    short8 bv11 = *(const short8*)&Abf[16 + l15][32 + q4 * 8];

    for (int it = 0; it < 32; ++it) {
        // ---- stage prefetched pair into LDS (fp32 -> bf16) ----
        {
            int q;
            q = t;
            *(uint2*)&Xbf[q >> 10][(q >> 4) & 63][(q & 15) * 4] =
                make_uint2(pk_bf16(r0.x, r0.y), pk_bf16(r0.z, r0.w));
            q = t + 512;
            *(uint2*)&Xbf[q >> 10][(q >> 4) & 63][(q & 15) * 4] =
                make_uint2(pk_bf16(r1.x, r1.y), pk_bf16(r1.z, r1.w));
            q = t + 1024;
            *(uint2*)&Xbf[q >> 10][(q >> 4) & 63][(q & 15) * 4] =
                make_uint2(pk_bf16(r2.x, r2.y), pk_bf16(r2.z, r2.w));
            q = t + 1536;
            *(uint2*)&Xbf[q >> 10][(q >> 4) & 63][(q & 15) * 4] =
                make_uint2(pk_bf16(r3.x, r3.y), pk_bf16(r3.z, r3.w));
        }
        __syncthreads();  // b1

        // issue next prefetch (hidden behind compute)
        if (it < 31) {
            const float4* src = (const float4*)(xb + (size_t)(it + 1) * 8192);
            r0 = src[t]; r1 = src[t + 512]; r2 = src[t + 1024]; r3 = src[t + 1536];
        }

        // ---- phase V (MFMA): v[m][k] = sum_p X[m][p] * A[k][p] ----
        // wave: slab sl, m-tile m0; both k-tiles; K-chunks p in [0,32),[32,64)
        {
            short8 xa0 = *(const short8*)&Xbf[sl][m0 + l15][q4 * 8];
            short8 xa1 = *(const short8*)&Xbf[sl][m0 + l15][32 + q4 * 8];
            f32x4 z = {0.f, 0.f, 0.f, 0.f};
            f32x4 v0 = __builtin_amdgcn_mfma_f32_16x16x32_bf16(xa0, bv00, z, 0, 0, 0);
            v0 = __builtin_amdgcn_mfma_f32_16x16x32_bf16(xa1, bv01, v0, 0, 0, 0);
            f32x4 v1 = __builtin_amdgcn_mfma_f32_16x16x32_bf16(xa0, bv10, z, 0, 0, 0);
            v1 = __builtin_amdgcn_mfma_f32_16x16x32_bf16(xa1, bv11, v1, 0, 0, 0);
            // D: row m = m0 + q4*4 + reg, col k = kt*16 + l15 -> Vbf[sl][k][m] bf16
            *(uint2*)&Vbf[sl][l15][m0 + q4 * 4] =
                make_uint2(pk_bf16(v0.x, v0.y), pk_bf16(v0.z, v0.w));
            *(uint2*)&Vbf[sl][16 + l15][m0 + q4 * 4] =
                make_uint2(pk_bf16(v1.x, v1.y), pk_bf16(v1.z, v1.w));
        }
        __syncthreads();  // b2

        // ---- phase U (MFMA): u[k][j] = sum_m v[k][m] * A[j][m] ----
        // wave: slab sl, k-tile kt2, j-tile jt; K-chunks m in [0,32),[32,64)
        {
            short8 va0 = *(const short8*)&Vbf[sl][kt2 * 16 + l15][q4 * 8];
            short8 va1 = *(const short8*)&Vbf[sl][kt2 * 16 + l15][32 + q4 * 8];
            f32x4 z = {0.f, 0.f, 0.f, 0.f};
            f32x4 u = __builtin_amdgcn_mfma_f32_16x16x32_bf16(
                va0, jt ? bv10 : bv00, z, 0, 0, 0);
            u = __builtin_amdgcn_mfma_f32_16x16x32_bf16(
                va1, jt ? bv11 : bv01, u, 0, 0, 0);
            // D: row k = kt2*16 + q4*4 + reg, col j = jt*16 + l15
            *(float4*)&Ubuf[sl][jt * 16 + l15][kt2 * 16 + q4 * 4] =
                make_float4(u.x, u.y, u.z, u.w);
        }
        __syncthreads();  // b3

        // ---- phase ACC (fp32 VALU): acc[i] += At[n][i] * u[j][k], both slabs ----
        {
            float u00 = Ubuf[0][j0][k32];
            float u01 = Ubuf[0][j0 + 16][k32];
            float u10 = Ubuf[1][j0][k32];
            float u11 = Ubuf[1][j0 + 16][k32];
            const float4* c0p = (const float4*)&Atl[2 * it][0];     // uniform -> bcast
            const float4* c1p = (const float4*)&Atl[2 * it + 1][0];
#pragma unroll
            for (int i4 = 0; i4 < 8; ++i4) {
                float4 c0 = c0p[i4];
                float4 c1 = c1p[i4];
                acc0[i4 * 4 + 0] += c0.x * u00 + c1.x * u10;
                acc0[i4 * 4 + 1] += c0.y * u00 + c1.y * u10;
                acc0[i4 * 4 + 2] += c0.z * u00 + c1.z * u10;
                acc0[i4 * 4 + 3] += c0.w * u00 + c1.w * u10;
                acc1[i4 * 4 + 0] += c0.x * u01 + c1.x * u11;
                acc1[i4 * 4 + 1] += c0.y * u01 + c1.y * u11;
                acc1[i4 * 4 + 2] += c0.z * u01 + c1.z * u11;
                acc1[i4 * 4 + 3] += c0.w * u01 + c1.w * u11;
            }
        }
    }

    // ---- epilogue: out[b][i][j][k] ----
    float* ob = out + (size_t)b * 32768;
#pragma unroll
    for (int i = 0; i < 32; ++i) {
        ob[i * 1024 + j0 * 32 + k32]        = acc0[i];
        ob[i * 1024 + (j0 + 16) * 32 + k32] = acc1[i];
    }
}

extern "C" void kernel_launch(void* const* d_in, const int* in_sizes, int n_in,
                              void* d_out, int out_size, void* d_ws, size_t ws_size,
                              hipStream_t stream) {
    const float* x = (const float*)d_in[0];
    float* out = (float*)d_out;
    float* ws  = (float*)d_ws;   // [0,2048): A ; [2048,4096): At

    init_A<<<2, 1024, 0, stream>>>(ws);
    spectral_kernel<<<256, 512, 0, stream>>>(x, ws, out);
}